// Round 1
// baseline (511.135 us; speedup 1.0000x reference)
//
#include <hip/hip_runtime.h>

#define BATCH 512
#define NC 3
#define TT 4096
#define HH 17

__device__ __forceinline__ float bcast(float v, int lane) {
    return __uint_as_float(__builtin_amdgcn_readlane(__float_as_uint(v), lane));
}

// tanh(x) = 1 - 2/(exp(2x)+1); exact saturation at +/-1, ~1e-7 abs error
__device__ __forceinline__ float fast_tanh(float x) {
    float e = __expf(2.0f * x);
    float r = __builtin_amdgcn_rcpf(e + 1.0f);
    return fmaf(-2.0f, r, 1.0f);
}

template <int DIR>
__device__ float run_rnn(const float4* __restrict__ x0,
                         const float4* __restrict__ x1,
                         const float4* __restrict__ x2,
                         const float* __restrict__ W_ih,
                         const float* __restrict__ W_hh,
                         const float* __restrict__ b_ih,
                         const float* __restrict__ b_hh,
                         int row) {
    float w[HH];
#pragma unroll
    for (int j = 0; j < HH; ++j) w[j] = W_hh[row * HH + j];
    const float wx0 = W_ih[row * NC + 0];
    const float wx1 = W_ih[row * NC + 1];
    const float wx2 = W_ih[row * NC + 2];
    const float bias = b_ih[row] + b_hh[row];

    float h[HH];
#pragma unroll
    for (int j = 0; j < HH; ++j) h[j] = 0.0f;
    float hsum = 0.0f;

    const int NB = TT / 4;
    int t4 = DIR ? NB - 1 : 0;
    float4 ca = x0[t4], cbv = x1[t4], ccv = x2[t4];

    for (int blk = 0; blk < NB; ++blk) {
        int nxt = (blk + 1 < NB) ? blk + 1 : blk;  // clamped prefetch
        int t4n = DIR ? NB - 1 - nxt : nxt;
        float4 na = x0[t4n], nbv = x1[t4n], ncv = x2[t4n];

        float xa[4] = {ca.x, ca.y, ca.z, ca.w};
        float xb[4] = {cbv.x, cbv.y, cbv.z, cbv.w};
        float xc[4] = {ccv.x, ccv.y, ccv.z, ccv.w};

#pragma unroll
        for (int k = 0; k < 4; ++k) {
            const int kk = DIR ? (3 - k) : k;  // compile-time constant index
            // input projection + bias
            float a0 = fmaf(wx0, xa[kk], bias);
            a0 = fmaf(wx1, xb[kk], a0);
            a0 = fmaf(wx2, xc[kk], a0);
            // W_hh row-dot h, 4 accumulator chains to expose ILP
            float a1 = 0.0f, a2 = 0.0f, a3 = 0.0f;
#pragma unroll
            for (int j = 0; j < 16; j += 4) {
                a0 = fmaf(w[j + 0], h[j + 0], a0);
                a1 = fmaf(w[j + 1], h[j + 1], a1);
                a2 = fmaf(w[j + 2], h[j + 2], a2);
                a3 = fmaf(w[j + 3], h[j + 3], a3);
            }
            a0 = fmaf(w[16], h[16], a0);
            float s = (a0 + a1) + (a2 + a3);
            float hn = fast_tanh(s);
            hsum += hn;  // running time-sum of this lane's hidden component
            // broadcast new hidden state to all lanes (uniform -> SGPRs)
#pragma unroll
            for (int j = 0; j < HH; ++j) h[j] = bcast(hn, j);
        }
        ca = na; cbv = nbv; ccv = ncv;
    }
    return hsum;
}

__global__ __launch_bounds__(64) void rnn_kernel(
    const float* __restrict__ x,
    const float* __restrict__ W_ih_f, const float* __restrict__ W_hh_f,
    const float* __restrict__ b_ih_f, const float* __restrict__ b_hh_f,
    const float* __restrict__ W_ih_b, const float* __restrict__ W_hh_b,
    const float* __restrict__ b_ih_b, const float* __restrict__ b_hh_b,
    float* __restrict__ partial) {
    int wid = blockIdx.x;       // 0..1023  (batch, dir)
    int b = wid >> 1;
    int dir = wid & 1;
    int lane = threadIdx.x;     // 0..63, rows 0..16 are live
    int row = lane < HH ? lane : HH - 1;

    const float* xb = x + (size_t)b * NC * TT;
    const float4* x0 = reinterpret_cast<const float4*>(xb);
    const float4* x1 = reinterpret_cast<const float4*>(xb + TT);
    const float4* x2 = reinterpret_cast<const float4*>(xb + 2 * TT);

    float hsum;
    if (dir == 0)
        hsum = run_rnn<0>(x0, x1, x2, W_ih_f, W_hh_f, b_ih_f, b_hh_f, row);
    else
        hsum = run_rnn<1>(x0, x1, x2, W_ih_b, W_hh_b, b_ih_b, b_hh_b, row);

    if (lane < HH) partial[wid * HH + lane] = hsum;
}

__global__ void finalize_kernel(const float* __restrict__ partial,
                                const float* __restrict__ conv_w,
                                const float* __restrict__ conv_b,
                                float* __restrict__ out) {
    int b = blockIdx.x * blockDim.x + threadIdx.x;
    if (b >= BATCH) return;
    const float* pf = partial + (size_t)(b * 2 + 0) * HH;
    const float* pb = partial + (size_t)(b * 2 + 1) * HH;
    const float inv = 1.0f / (float)TT;
#pragma unroll
    for (int o = 0; o < 2; ++o) {
        float s = 0.0f;
#pragma unroll
        for (int i = 0; i < HH; ++i) s += conv_w[o * 2 * HH + i] * pf[i];
#pragma unroll
        for (int i = 0; i < HH; ++i) s += conv_w[o * 2 * HH + HH + i] * pb[i];
        out[b * 2 + o] = fmaf(s, inv, conv_b[o]);
    }
}

extern "C" void kernel_launch(void* const* d_in, const int* in_sizes, int n_in,
                              void* d_out, int out_size, void* d_ws, size_t ws_size,
                              hipStream_t stream) {
    const float* x      = (const float*)d_in[0];
    const float* W_ih_f = (const float*)d_in[1];
    const float* W_hh_f = (const float*)d_in[2];
    const float* b_ih_f = (const float*)d_in[3];
    const float* b_hh_f = (const float*)d_in[4];
    const float* W_ih_b = (const float*)d_in[5];
    const float* W_hh_b = (const float*)d_in[6];
    const float* b_ih_b = (const float*)d_in[7];
    const float* b_hh_b = (const float*)d_in[8];
    const float* conv_w = (const float*)d_in[9];
    const float* conv_b = (const float*)d_in[10];

    float* partial = (float*)d_ws;  // 1024 * 17 floats = 68 KB
    float* out = (float*)d_out;

    rnn_kernel<<<dim3(BATCH * 2), dim3(64), 0, stream>>>(
        x, W_ih_f, W_hh_f, b_ih_f, b_hh_f, W_ih_b, W_hh_b, b_ih_b, b_hh_b, partial);
    finalize_kernel<<<dim3((BATCH + 255) / 256), dim3(256), 0, stream>>>(
        partial, conv_w, conv_b, out);
}